// Round 5
// baseline (178.281 us; speedup 1.0000x reference)
//
#include <hip/hip_runtime.h>
#include <hip/hip_bf16.h>

#define TGT 256
#define BSZ 8
#define E   256
#define SRC 4096

typedef __attribute__((ext_vector_type(8))) short           bf16x8;
typedef __attribute__((ext_vector_type(4))) float           f32x4;
typedef __attribute__((ext_vector_type(4))) float           f4;
typedef __attribute__((ext_vector_type(4))) unsigned short  u16x4;

__device__ inline unsigned short f2b(float x) {
    union { __hip_bfloat16 h; unsigned short u; } cv;
    cv.h = __float2bfloat16(x);
    return cv.u;
}

// load 8 contiguous floats, convert to bf16x8 fragment
__device__ inline bf16x8 cvt8v(const float* __restrict__ p) {
    f4 lo = *(const f4*)p;
    f4 hi = *(const f4*)(p + 4);
    bf16x8 r;
    #pragma unroll
    for (int j = 0; j < 4; ++j) {
        r[j]     = (short)f2b(lo[j]);
        r[4 + j] = (short)f2b(hi[j]);
    }
    return r;
}

// ---------------------------------------------------------------------------
// Kernel 1: fully fused  (a) out1 = mask  (b) part[kc] = M_b[t-tile,kc] @ V_b[kc]
// with V transposed fp32->bf16 IN-LDS (no separate transpose kernel, no vt).
//
// Block = (b, tt: 32-row t-tile, kc: 1024-wide K chunk); 256 blocks, 512 thr.
//   A (mask): double-buffered LDS, staged at 128-k granularity; mask read once,
//             out1 written in the same pass (verbatim copy fused).
//   B (V^T):  double-buffered LDS, staged at 32-k granularity; global reads
//             along e (coalesced), per-thread pack -> ds_write_b64 transposed.
//   8 waves each own 32 E-columns -> no cross-wave reduction; fp32 K-partials
//   summed in kernel 2.
// LDS: A 2*32*136*2B = 17.0 KB + V 2*256*40*2B = 40.0 KB = 57.4 KB (<64 KB).
// ---------------------------------------------------------------------------
#define AP 136   // A pitch (u16): 272B rows, b128-aligned
#define VP 40    // V pitch (u16): 80B rows,  b128-aligned

__global__ __launch_bounds__(512) void gemm1_fused(
    const float* __restrict__ value,
    const float* __restrict__ mask,
    float* __restrict__ out1,
    float* __restrict__ part)
{
    __shared__ unsigned short As[2][32 * AP];
    __shared__ unsigned short Vs[2][256 * VP];

    const int bx  = blockIdx.x;
    const int b   = bx & 7;              // XCD swizzle: per-b V chunk stays in one L2
    const int tt  = (bx >> 3) & 7;
    const int kc  = bx >> 6;             // 0..3
    const int t0  = tt * 32;
    const int k0  = kc * 1024;
    const int tid = threadIdx.x;
    const int w    = tid >> 6;
    const int lane = tid & 63;
    const int quad = lane >> 4;
    const int l15  = lane & 15;

    // ---- A staging roles: 32 rows x 128 k per ksA; thread -> 2 f4
    const int sr0 = tid >> 5;            // 0..15
    const int sr1 = sr0 + 16;            // 16..31
    const int sc  = (tid & 31) * 4;      // k-offset 0..124
    const float* mbase = mask + (size_t)b * TGT * SRC + (size_t)t0 * SRC + k0;
    float*       obase = out1 + (size_t)b * TGT * SRC + (size_t)t0 * SRC + k0;

    // ---- V staging roles: 32 k x 256 e per substep; thread -> fixed e, 16 k
    const int ve  = tid & 255;
    const int vkg = (tid >> 8) * 16;     // 0 or 16
    const float* vbase = value + (size_t)k0 * (BSZ * E) + (size_t)b * E + ve;

    f32x4 acc00 = {}, acc01 = {}, acc10 = {}, acc11 = {};

    // ---------------- prologue: stage A(0) and V(0)
    {
        f4 v0 = *(const f4*)(mbase + (size_t)sr0 * SRC + sc);
        f4 v1 = *(const f4*)(mbase + (size_t)sr1 * SRC + sc);
        *(f4*)(obase + (size_t)sr0 * SRC + sc) = v0;
        *(f4*)(obase + (size_t)sr1 * SRC + sc) = v1;
        unsigned short* d0 = &As[0][sr0 * AP + sc];
        unsigned short* d1 = &As[0][sr1 * AP + sc];
        #pragma unroll
        for (int j = 0; j < 4; ++j) { d0[j] = f2b(v0[j]); d1[j] = f2b(v1[j]); }

        const float* vp = vbase + (size_t)vkg * (BSZ * E);
        float vv[16];
        #pragma unroll
        for (int i = 0; i < 16; ++i) vv[i] = vp[(size_t)i * (BSZ * E)];
        #pragma unroll
        for (int g = 0; g < 4; ++g) {
            u16x4 pk;
            #pragma unroll
            for (int c = 0; c < 4; ++c) pk[c] = f2b(vv[g * 4 + c]);
            *(u16x4*)&Vs[0][ve * VP + vkg + g * 4] = pk;
        }
    }
    __syncthreads();

    // ---------------- main loop: 32 substeps of 32 k
    for (int s = 0; s < 32; ++s) {
        const int vb = s & 1;
        const int ab = (s >> 2) & 1;
        const int haveV = (s < 31);
        const int haveA = ((s & 3) == 0) && (s < 28);

        // issue next-V global loads (latency overlapped with MFMA below)
        float vv[16];
        if (haveV) {
            const float* vp = vbase + (size_t)((s + 1) * 32 + vkg) * (BSZ * E);
            #pragma unroll
            for (int i = 0; i < 16; ++i) vv[i] = vp[(size_t)i * (BSZ * E)];
        }
        // issue next-A global loads
        f4 a0v, a1v;
        if (haveA) {
            int ka = ((s >> 2) + 1) * 128;
            a0v = *(const f4*)(mbase + (size_t)sr0 * SRC + ka + sc);
            a1v = *(const f4*)(mbase + (size_t)sr1 * SRC + ka + sc);
        }

        // compute substep s
        {
            const int koff = (s & 3) * 32 + quad * 8;
            bf16x8 a0 = *(const bf16x8*)&As[ab][ l15       * AP + koff];
            bf16x8 a1 = *(const bf16x8*)&As[ab][(l15 + 16) * AP + koff];
            bf16x8 b0 = *(const bf16x8*)&Vs[vb][(w * 32 + l15)      * VP + quad * 8];
            bf16x8 b1 = *(const bf16x8*)&Vs[vb][(w * 32 + l15 + 16) * VP + quad * 8];
            acc00 = __builtin_amdgcn_mfma_f32_16x16x32_bf16(a0, b0, acc00, 0, 0, 0);
            acc01 = __builtin_amdgcn_mfma_f32_16x16x32_bf16(a0, b1, acc01, 0, 0, 0);
            acc10 = __builtin_amdgcn_mfma_f32_16x16x32_bf16(a1, b0, acc10, 0, 0, 0);
            acc11 = __builtin_amdgcn_mfma_f32_16x16x32_bf16(a1, b1, acc11, 0, 0, 0);
        }

        // drain staged data into the other buffers
        if (haveA) {
            int ka = ((s >> 2) + 1) * 128;
            *(f4*)(obase + (size_t)sr0 * SRC + ka + sc) = a0v;
            *(f4*)(obase + (size_t)sr1 * SRC + ka + sc) = a1v;
            unsigned short* d0 = &As[ab ^ 1][sr0 * AP + sc];
            unsigned short* d1 = &As[ab ^ 1][sr1 * AP + sc];
            #pragma unroll
            for (int j = 0; j < 4; ++j) { d0[j] = f2b(a0v[j]); d1[j] = f2b(a1v[j]); }
        }
        if (haveV) {
            #pragma unroll
            for (int g = 0; g < 4; ++g) {
                u16x4 pk;
                #pragma unroll
                for (int c = 0; c < 4; ++c) pk[c] = f2b(vv[g * 4 + c]);
                *(u16x4*)&Vs[vb ^ 1][ve * VP + vkg + g * 4] = pk;
            }
        }
        __syncthreads();
    }

    // epilogue: wave-private 32x32 fp32 partial
    // D layout: col = lane&15, row = quad*4 + reg  [verified m89/m91]
    float* pb = part + ((size_t)kc * BSZ + b) * TGT * E;
    #pragma unroll
    for (int r = 0; r < 4; ++r) {
        int rr0 = t0 + quad * 4 + r;
        int rr1 = rr0 + 16;
        int c0  = w * 32 + l15;
        pb[(size_t)rr0 * E + c0]      = acc00[r];
        pb[(size_t)rr0 * E + c0 + 16] = acc01[r];
        pb[(size_t)rr1 * E + c0]      = acc10[r];
        pb[(size_t)rr1 * E + c0 + 16] = acc11[r];
    }
}

// ---------------------------------------------------------------------------
// Kernel 2: out0[t,b,:] = (sum_kc part[kc])[b,t,:] @ W^T + bias
// wave per 16x16 tile; A = fp32 4-partial sum -> bf16; B = fp32 W -> bf16.
// ---------------------------------------------------------------------------
#define PSTRIDE ((size_t)BSZ * TGT * E)

__global__ __launch_bounds__(256) void gemm2(
    const float* __restrict__ part,
    const float* __restrict__ wgt,
    const float* __restrict__ bias,
    float* __restrict__ out0)
{
    const int tid  = threadIdx.x;
    const int wv   = tid >> 6;
    const int lane = tid & 63;
    const int tau  = blockIdx.x * 4 + wv;   // 0..2047
    const int b    = tau >> 8;
    const int rem  = tau & 255;
    const int t0   = (rem >> 4) * 16;
    const int e0   = (rem & 15) * 16;
    const int quad = lane >> 4;
    const int l15  = lane & 15;

    const float* arow = part + (size_t)b * TGT * E + (size_t)(t0 + l15) * E + quad * 8;
    const float* brow = wgt + (size_t)(e0 + l15) * E + quad * 8;

    f32x4 acc = {};
    #pragma unroll
    for (int ks = 0; ks < 8; ++ks) {
        const float* ap = arow + ks * 32;
        f4 lo = *(const f4*)(ap);
        f4 hi = *(const f4*)(ap + 4);
        #pragma unroll
        for (int p = 1; p < 4; ++p) {
            lo += *(const f4*)(ap + p * PSTRIDE);
            hi += *(const f4*)(ap + p * PSTRIDE + 4);
        }
        bf16x8 a;
        #pragma unroll
        for (int j = 0; j < 4; ++j) {
            a[j]     = (short)f2b(lo[j]);
            a[4 + j] = (short)f2b(hi[j]);
        }
        bf16x8 bb = cvt8v(brow + ks * 32);
        acc = __builtin_amdgcn_mfma_f32_16x16x32_bf16(a, bb, acc, 0, 0, 0);
    }

    const float bval = bias[e0 + l15];
    #pragma unroll
    for (int r = 0; r < 4; ++r) {
        int t = t0 + quad * 4 + r;
        int e = e0 + l15;
        out0[(size_t)t * (BSZ * E) + (size_t)b * E + e] = acc[r] + bval;
    }
}

// ---------------------------------------------------------------------------
extern "C" void kernel_launch(void* const* d_in, const int* in_sizes, int n_in,
                              void* d_out, int out_size, void* d_ws, size_t ws_size,
                              hipStream_t stream)
{
    // inputs: 0=query(unused) 1=key(unused) 2=value 3=proposal_mask 4=W 5=bias
    const float* value = (const float*)d_in[2];
    const float* mask  = (const float*)d_in[3];
    const float* wgt   = (const float*)d_in[4];
    const float* bias  = (const float*)d_in[5];

    float* out0 = (float*)d_out;                              // (256,8,256)
    float* out1 = (float*)d_out + (size_t)TGT * BSZ * E;      // (8,256,4096)

    // ws layout: part fp32 [4][b][t][e] (8 MB)
    float* part = (float*)d_ws;

    gemm1_fused<<<256, 512, 0, stream>>>(value, mask, out1, part);
    gemm2<<<512, 256, 0, stream>>>(part, wgt, bias, out0);
}

// Round 6
// 152.837 us; speedup vs baseline: 1.1665x; 1.1665x over previous
//
#include <hip/hip_runtime.h>
#include <hip/hip_bf16.h>

#define TGT 256
#define BSZ 8
#define E   256
#define SRC 4096

typedef __attribute__((ext_vector_type(8))) short           bf16x8;
typedef __attribute__((ext_vector_type(4))) float           f32x4;
typedef __attribute__((ext_vector_type(4))) float           f4;
typedef __attribute__((ext_vector_type(8))) unsigned short  u16x8;

__device__ inline unsigned short f2b(float x) {
    union { __hip_bfloat16 h; unsigned short u; } cv;
    cv.h = __float2bfloat16(x);
    return cv.u;
}

__device__ inline bf16x8 cvt8v(const float* __restrict__ p) {
    f4 lo = *(const f4*)p;
    f4 hi = *(const f4*)(p + 4);
    bf16x8 r;
    #pragma unroll
    for (int j = 0; j < 4; ++j) { r[j] = (short)f2b(lo[j]); r[4 + j] = (short)f2b(hi[j]); }
    return r;
}

// ---------------------------------------------------------------------------
// v_frag: value(SRC,BSZ,E) fp32 -> vtf in B-fragment order (bf16):
//   vtf[(((b*16+et)*128 + ks)*64 + lane)*8 + j] = V_b[k][n],
//   n = et*16 + (lane&15), k = ks*32 + (lane>>4)*8 + j.
// Block = (64-k chunk, b). Coalesced reads; frag writes 16B/lane coalesced.
// ---------------------------------------------------------------------------
__global__ __launch_bounds__(256) void v_frag(
    const float* __restrict__ value, unsigned short* __restrict__ vtf)
{
    __shared__ unsigned short tile[64 * 264];   // pitch 264 u16 (528B, 16B-aligned)
    const int kch = blockIdx.x;                 // 0..63
    const int b   = blockIdx.y;
    const int k0  = kch * 64;
    const int tid = threadIdx.x;

    #pragma unroll
    for (int i = 0; i < 16; ++i) {
        int lin = i * 256 + tid;                // 0..4095
        int row = lin >> 6;                     // k-local 0..63
        int c4  = lin & 63;                     // e float4 idx
        f4 v = *(const f4*)(value + (size_t)(k0 + row) * (BSZ * E)
                                  + (size_t)b * E + c4 * 4);
        #pragma unroll
        for (int j = 0; j < 4; ++j) tile[row * 264 + c4 * 4 + j] = f2b(v[j]);
    }
    __syncthreads();

    #pragma unroll
    for (int i = 0; i < 8; ++i) {
        int o    = i * 256 + tid;               // 0..2047 octets
        int et   = o >> 7;
        int ksl  = (o >> 6) & 1;
        int lane = o & 63;
        int quad = lane >> 4, l15 = lane & 15;
        u16x8 pk;
        #pragma unroll
        for (int j = 0; j < 8; ++j)
            pk[j] = tile[(ksl * 32 + quad * 8 + j) * 264 + et * 16 + l15];
        size_t ks = (size_t)kch * 2 + ksl;
        *(u16x8*)&vtf[((((size_t)b * 16 + et) * 128 + ks) * 64 + lane) * 8] = pk;
    }
}

// ---------------------------------------------------------------------------
// w_frag: W(E,E) fp32 -> wf in B-fragment order (bf16):
//   wf[((et*8 + ks)*64 + lane)*8 + j] = W[et*16+(lane&15)][ks*32+(lane>>4)*8+j]
// ---------------------------------------------------------------------------
__global__ __launch_bounds__(256) void w_frag(
    const float* __restrict__ wgt, unsigned short* __restrict__ wf)
{
    int o    = blockIdx.x * 256 + threadIdx.x;  // 0..8191
    int et   = o >> 9;
    int ks   = (o >> 6) & 7;
    int lane = o & 63;
    int quad = lane >> 4, l15 = lane & 15;
    bf16x8 v = cvt8v(wgt + (size_t)(et * 16 + l15) * E + ks * 32 + quad * 8);
    *(bf16x8*)&wf[(size_t)o * 8] = v;
}

// ---------------------------------------------------------------------------
// gemm1: part[kc] = M_b[t-tile, kc-chunk] @ V_b[kc-chunk]  + fused out1 copy.
// Block = (b, tt, kc): 8*8*8 = 512 blocks (2/CU), 512 thr.
// A (mask fp32): coalesced read -> out1 write + cvt -> LDS dbuf (4 stages).
// B: coalesced frag streams from vtf (L2-resident per XCD via b=bx&7).
// ---------------------------------------------------------------------------
#define AP 136   // A pitch u16: 272 B rows (16B-aligned)

__global__ __launch_bounds__(512) void gemm1(
    const float* __restrict__ mask,
    const unsigned short* __restrict__ vtf,
    float* __restrict__ out1,
    float* __restrict__ part)
{
    __shared__ unsigned short As[2][32 * AP];   // 2 x 8.7 KB
    const int bx  = blockIdx.x;
    const int b   = bx & 7;                     // XCD swizzle
    const int tt  = (bx >> 3) & 7;
    const int kc  = bx >> 6;                    // 0..7, K-chunk 512
    const int t0  = tt * 32;
    const int k0  = kc * 512;
    const int tid = threadIdx.x;
    const int w    = tid >> 6;
    const int lane = tid & 63;
    const int quad = lane >> 4;
    const int l15  = lane & 15;

    const float* mbase = mask + (size_t)b * TGT * SRC + (size_t)t0 * SRC + k0;
    float*       obase = out1 + (size_t)b * TGT * SRC + (size_t)t0 * SRC + k0;
    const int sr0 = tid >> 5, sr1 = sr0 + 16, sc = (tid & 31) * 4;

    // wave w owns e columns [w*32, w*32+32): et pair (2w, 2w+1)
    const unsigned short* bfr0 = vtf + (((size_t)b * 16 + 2 * w) * 128 + (size_t)kc * 16) * 512;
    const unsigned short* bfr1 = bfr0 + (size_t)128 * 512;

    // prologue: stage A(0)
    {
        f4 v0 = *(const f4*)(mbase + (size_t)sr0 * SRC + sc);
        f4 v1 = *(const f4*)(mbase + (size_t)sr1 * SRC + sc);
        *(f4*)(obase + (size_t)sr0 * SRC + sc) = v0;
        *(f4*)(obase + (size_t)sr1 * SRC + sc) = v1;
        unsigned short* d0 = &As[0][sr0 * AP + sc];
        unsigned short* d1 = &As[0][sr1 * AP + sc];
        #pragma unroll
        for (int j = 0; j < 4; ++j) { d0[j] = f2b(v0[j]); d1[j] = f2b(v1[j]); }
    }
    __syncthreads();

    f32x4 acc00 = {}, acc01 = {}, acc10 = {}, acc11 = {};

    #pragma unroll
    for (int s = 0; s < 4; ++s) {               // 4 stages x 128 k
        // prefetch next A stage (global, overlapped with MFMAs below)
        f4 a0v, a1v;
        if (s < 3) {
            a0v = *(const f4*)(mbase + (size_t)sr0 * SRC + (s + 1) * 128 + sc);
            a1v = *(const f4*)(mbase + (size_t)sr1 * SRC + (s + 1) * 128 + sc);
        }
        // compute stage s: 4 k-steps
        #pragma unroll
        for (int q = 0; q < 4; ++q) {
            bf16x8 B0 = *(const bf16x8*)(bfr0 + ((size_t)(s * 4 + q) * 64 + lane) * 8);
            bf16x8 B1 = *(const bf16x8*)(bfr1 + ((size_t)(s * 4 + q) * 64 + lane) * 8);
            bf16x8 a0 = *(const bf16x8*)&As[s & 1][ l15       * AP + q * 32 + quad * 8];
            bf16x8 a1 = *(const bf16x8*)&As[s & 1][(l15 + 16) * AP + q * 32 + quad * 8];
            acc00 = __builtin_amdgcn_mfma_f32_16x16x32_bf16(a0, B0, acc00, 0, 0, 0);
            acc01 = __builtin_amdgcn_mfma_f32_16x16x32_bf16(a0, B1, acc01, 0, 0, 0);
            acc10 = __builtin_amdgcn_mfma_f32_16x16x32_bf16(a1, B0, acc10, 0, 0, 0);
            acc11 = __builtin_amdgcn_mfma_f32_16x16x32_bf16(a1, B1, acc11, 0, 0, 0);
        }
        if (s < 3) {
            *(f4*)(obase + (size_t)sr0 * SRC + (s + 1) * 128 + sc) = a0v;
            *(f4*)(obase + (size_t)sr1 * SRC + (s + 1) * 128 + sc) = a1v;
            unsigned short* d0 = &As[(s + 1) & 1][sr0 * AP + sc];
            unsigned short* d1 = &As[(s + 1) & 1][sr1 * AP + sc];
            #pragma unroll
            for (int j = 0; j < 4; ++j) { d0[j] = f2b(a0v[j]); d1[j] = f2b(a1v[j]); }
        }
        __syncthreads();
    }

    // epilogue: wave-private 32x32 fp32 partial
    // D layout: col = lane&15 (n), row = quad*4 + reg (m)  [verified m89/m91]
    float* pb = part + ((size_t)kc * BSZ + b) * TGT * E;
    #pragma unroll
    for (int r = 0; r < 4; ++r) {
        int rr0 = t0 + quad * 4 + r;
        int rr1 = rr0 + 16;
        int c0  = w * 32 + l15;
        pb[(size_t)rr0 * E + c0]      = acc00[r];
        pb[(size_t)rr0 * E + c0 + 16] = acc01[r];
        pb[(size_t)rr1 * E + c0]      = acc10[r];
        pb[(size_t)rr1 * E + c0 + 16] = acc11[r];
    }
}

// ---------------------------------------------------------------------------
// reduce: credf (A-frag order, bf16) = sum over 8 K-partials (fp32).
//   credf[(((b*16+tt16)*8 + ks)*64 + lane)*8 + j] = cred[b][tt16*16+(lane&15)]
//                                                       [ks*32+(lane>>4)*8+j]
// ---------------------------------------------------------------------------
#define PSTRIDE ((size_t)BSZ * TGT * E)

__global__ __launch_bounds__(256) void reduce_part(
    const float* __restrict__ part, unsigned short* __restrict__ credf)
{
    int o    = blockIdx.x * 256 + threadIdx.x;  // 0..65535 octets
    int b    = o >> 13;
    int tt16 = (o >> 9) & 15;
    int ks   = (o >> 6) & 7;
    int lane = o & 63;
    int quad = lane >> 4, l15 = lane & 15;
    const float* ap = part + (size_t)b * TGT * E
                    + (size_t)(tt16 * 16 + l15) * E + ks * 32 + quad * 8;
    f4 lo = *(const f4*)ap;
    f4 hi = *(const f4*)(ap + 4);
    #pragma unroll
    for (int p = 1; p < 8; ++p) {
        lo += *(const f4*)(ap + p * PSTRIDE);
        hi += *(const f4*)(ap + p * PSTRIDE + 4);
    }
    u16x8 pk;
    #pragma unroll
    for (int j = 0; j < 4; ++j) { pk[j] = f2b(lo[j]); pk[4 + j] = f2b(hi[j]); }
    *(u16x8*)&credf[(size_t)o * 8] = pk;
}

// ---------------------------------------------------------------------------
// gemm2: out0[t,b,:] = cred[b,t,:] @ W^T + bias.  Both operands frag-ordered.
// ---------------------------------------------------------------------------
__global__ __launch_bounds__(256) void gemm2(
    const unsigned short* __restrict__ credf,
    const unsigned short* __restrict__ wf,
    const float* __restrict__ bias,
    float* __restrict__ out0)
{
    const int tid  = threadIdx.x;
    const int wv   = tid >> 6;
    const int lane = tid & 63;
    const int tau  = blockIdx.x * 4 + wv;   // 0..2047
    const int b    = tau >> 8;
    const int rem  = tau & 255;
    const int tt16 = rem >> 4;
    const int et   = rem & 15;
    const int quad = lane >> 4;
    const int l15  = lane & 15;

    const unsigned short* af = credf + (((size_t)b * 16 + tt16) * 8) * 512 + (size_t)lane * 8;
    const unsigned short* bf = wf + ((size_t)et * 8) * 512 + (size_t)lane * 8;

    f32x4 acc = {};
    #pragma unroll
    for (int ks = 0; ks < 8; ++ks) {
        bf16x8 a  = *(const bf16x8*)(af + (size_t)ks * 512);
        bf16x8 bb = *(const bf16x8*)(bf + (size_t)ks * 512);
        acc = __builtin_amdgcn_mfma_f32_16x16x32_bf16(a, bb, acc, 0, 0, 0);
    }

    const float bval = bias[et * 16 + l15];
    #pragma unroll
    for (int r = 0; r < 4; ++r) {
        int t = tt16 * 16 + quad * 4 + r;
        int e = et * 16 + l15;
        out0[(size_t)t * (BSZ * E) + (size_t)b * E + e] = acc[r] + bval;
    }
}

// ---------------------------------------------------------------------------
extern "C" void kernel_launch(void* const* d_in, const int* in_sizes, int n_in,
                              void* d_out, int out_size, void* d_ws, size_t ws_size,
                              hipStream_t stream)
{
    // inputs: 0=query(unused) 1=key(unused) 2=value 3=proposal_mask 4=W 5=bias
    const float* value = (const float*)d_in[2];
    const float* mask  = (const float*)d_in[3];
    const float* wgt   = (const float*)d_in[4];
    const float* bias  = (const float*)d_in[5];

    float* out0 = (float*)d_out;                              // (256,8,256)
    float* out1 = (float*)d_out + (size_t)TGT * BSZ * E;      // (8,256,4096)

    // ws layout: vtf bf16 16.8MB | wf bf16 128KB | part fp32 16.8MB | credf 1MB
    unsigned short* vtf   = (unsigned short*)d_ws;
    unsigned short* wf    = vtf + (size_t)BSZ * E * SRC;
    float*          part  = (float*)(wf + (size_t)16 * 8 * 64 * 8);
    unsigned short* credf = (unsigned short*)(part + (size_t)8 * BSZ * TGT * E);

    v_frag<<<dim3(64, BSZ), 256, 0, stream>>>(value, vtf);
    w_frag<<<32, 256, 0, stream>>>(wgt, wf);
    gemm1<<<512, 512, 0, stream>>>(mask, vtf, out1, part);
    reduce_part<<<256, 256, 0, stream>>>(part, credf);
    gemm2<<<512, 256, 0, stream>>>(credf, wf, bias, out0);
}

// Round 7
// 150.134 us; speedup vs baseline: 1.1875x; 1.0180x over previous
//
#include <hip/hip_runtime.h>
#include <hip/hip_bf16.h>

#define TGT 256
#define BSZ 8
#define E   256
#define SRC 4096

typedef __attribute__((ext_vector_type(8))) short           bf16x8;
typedef __attribute__((ext_vector_type(4))) float           f32x4;
typedef __attribute__((ext_vector_type(4))) float           f4;
typedef __attribute__((ext_vector_type(8))) unsigned short  u16x8;

__device__ inline unsigned short f2b(float x) {
    union { __hip_bfloat16 h; unsigned short u; } cv;
    cv.h = __float2bfloat16(x);
    return cv.u;
}

__device__ inline bf16x8 cvt8v(const float* __restrict__ p) {
    f4 lo = *(const f4*)p;
    f4 hi = *(const f4*)(p + 4);
    bf16x8 r;
    #pragma unroll
    for (int j = 0; j < 4; ++j) { r[j] = (short)f2b(lo[j]); r[4 + j] = (short)f2b(hi[j]); }
    return r;
}

// ---------------------------------------------------------------------------
// prep: grid (64, 9).
//  by<8 : v_frag — value(SRC,BSZ,E) fp32 -> vtf in B-fragment order (bf16):
//     vtf[(((b*16+et)*128 + ks)*64 + lane)*8 + j] = V_b[k][n],
//     n = et*16 + (lane&15), k = ks*32 + (lane>>4)*8 + j.
//  by==8: w_frag — W(E,E) fp32 -> wf in B-fragment order (bf16):
//     wf[((et*8 + ks)*64 + lane)*8 + j] = W[et*16+(l15)][ks*32+quad*8+j]
// ---------------------------------------------------------------------------
__global__ __launch_bounds__(256) void prep(
    const float* __restrict__ value, const float* __restrict__ wgt,
    unsigned short* __restrict__ vtf, unsigned short* __restrict__ wf)
{
    const int tid = threadIdx.x;

    if (blockIdx.y == 8) {               // ---- W frag pass (64 tiny blocks)
        if (tid < 128) {
            int o    = blockIdx.x * 128 + tid;   // 0..8191
            int et   = o >> 9;
            int ks   = (o >> 6) & 7;
            int lane = o & 63;
            int quad = lane >> 4, l15 = lane & 15;
            bf16x8 v = cvt8v(wgt + (size_t)(et * 16 + l15) * E + ks * 32 + quad * 8);
            *(bf16x8*)&wf[(size_t)o * 8] = v;
        }
        return;
    }

    __shared__ unsigned short tile[64 * 264];   // pitch 264 u16 (528B, 16B-aligned)
    const int kch = blockIdx.x;                 // 0..63
    const int b   = blockIdx.y;
    const int k0  = kch * 64;

    #pragma unroll
    for (int i = 0; i < 16; ++i) {
        int lin = i * 256 + tid;                // 0..4095
        int row = lin >> 6;                     // k-local 0..63
        int c4  = lin & 63;                     // e float4 idx
        f4 v = *(const f4*)(value + (size_t)(k0 + row) * (BSZ * E)
                                  + (size_t)b * E + c4 * 4);
        #pragma unroll
        for (int j = 0; j < 4; ++j) tile[row * 264 + c4 * 4 + j] = f2b(v[j]);
    }
    __syncthreads();

    #pragma unroll
    for (int i = 0; i < 8; ++i) {
        int o    = i * 256 + tid;               // 0..2047 octets
        int et   = o >> 7;
        int ksl  = (o >> 6) & 1;
        int lane = o & 63;
        int quad = lane >> 4, l15 = lane & 15;
        u16x8 pk;
        #pragma unroll
        for (int j = 0; j < 8; ++j)
            pk[j] = tile[(ksl * 32 + quad * 8 + j) * 264 + et * 16 + l15];
        size_t ks = (size_t)kch * 2 + ksl;
        *(u16x8*)&vtf[((((size_t)b * 16 + et) * 128 + ks) * 64 + lane) * 8] = pk;
    }
}

// ---------------------------------------------------------------------------
// gemm1: part[kc] = M_b[t-tile, kc-chunk] @ V_b[kc-chunk]  + fused out1 copy.
// Block = (b, tt, kc): 8*8*8 = 512 blocks (2/CU), 512 thr.  [unchanged, r6]
// ---------------------------------------------------------------------------
#define AP 136   // A pitch u16: 272 B rows (16B-aligned)

__global__ __launch_bounds__(512) void gemm1(
    const float* __restrict__ mask,
    const unsigned short* __restrict__ vtf,
    float* __restrict__ out1,
    float* __restrict__ part)
{
    __shared__ unsigned short As[2][32 * AP];   // 2 x 8.7 KB
    const int bx  = blockIdx.x;
    const int b   = bx & 7;                     // XCD swizzle
    const int tt  = (bx >> 3) & 7;
    const int kc  = bx >> 6;                    // 0..7, K-chunk 512
    const int t0  = tt * 32;
    const int k0  = kc * 512;
    const int tid = threadIdx.x;
    const int w    = tid >> 6;
    const int lane = tid & 63;
    const int quad = lane >> 4;
    const int l15  = lane & 15;

    const float* mbase = mask + (size_t)b * TGT * SRC + (size_t)t0 * SRC + k0;
    float*       obase = out1 + (size_t)b * TGT * SRC + (size_t)t0 * SRC + k0;
    const int sr0 = tid >> 5, sr1 = sr0 + 16, sc = (tid & 31) * 4;

    // wave w owns e columns [w*32, w*32+32): et pair (2w, 2w+1)
    const unsigned short* bfr0 = vtf + (((size_t)b * 16 + 2 * w) * 128 + (size_t)kc * 16) * 512;
    const unsigned short* bfr1 = bfr0 + (size_t)128 * 512;

    // prologue: stage A(0)
    {
        f4 v0 = *(const f4*)(mbase + (size_t)sr0 * SRC + sc);
        f4 v1 = *(const f4*)(mbase + (size_t)sr1 * SRC + sc);
        *(f4*)(obase + (size_t)sr0 * SRC + sc) = v0;
        *(f4*)(obase + (size_t)sr1 * SRC + sc) = v1;
        unsigned short* d0 = &As[0][sr0 * AP + sc];
        unsigned short* d1 = &As[0][sr1 * AP + sc];
        #pragma unroll
        for (int j = 0; j < 4; ++j) { d0[j] = f2b(v0[j]); d1[j] = f2b(v1[j]); }
    }
    __syncthreads();

    f32x4 acc00 = {}, acc01 = {}, acc10 = {}, acc11 = {};

    #pragma unroll
    for (int s = 0; s < 4; ++s) {               // 4 stages x 128 k
        f4 a0v, a1v;
        if (s < 3) {
            a0v = *(const f4*)(mbase + (size_t)sr0 * SRC + (s + 1) * 128 + sc);
            a1v = *(const f4*)(mbase + (size_t)sr1 * SRC + (s + 1) * 128 + sc);
        }
        #pragma unroll
        for (int q = 0; q < 4; ++q) {
            bf16x8 B0 = *(const bf16x8*)(bfr0 + ((size_t)(s * 4 + q) * 64 + lane) * 8);
            bf16x8 B1 = *(const bf16x8*)(bfr1 + ((size_t)(s * 4 + q) * 64 + lane) * 8);
            bf16x8 a0 = *(const bf16x8*)&As[s & 1][ l15       * AP + q * 32 + quad * 8];
            bf16x8 a1 = *(const bf16x8*)&As[s & 1][(l15 + 16) * AP + q * 32 + quad * 8];
            acc00 = __builtin_amdgcn_mfma_f32_16x16x32_bf16(a0, B0, acc00, 0, 0, 0);
            acc01 = __builtin_amdgcn_mfma_f32_16x16x32_bf16(a0, B1, acc01, 0, 0, 0);
            acc10 = __builtin_amdgcn_mfma_f32_16x16x32_bf16(a1, B0, acc10, 0, 0, 0);
            acc11 = __builtin_amdgcn_mfma_f32_16x16x32_bf16(a1, B1, acc11, 0, 0, 0);
        }
        if (s < 3) {
            *(f4*)(obase + (size_t)sr0 * SRC + (s + 1) * 128 + sc) = a0v;
            *(f4*)(obase + (size_t)sr1 * SRC + (s + 1) * 128 + sc) = a1v;
            unsigned short* d0 = &As[(s + 1) & 1][sr0 * AP + sc];
            unsigned short* d1 = &As[(s + 1) & 1][sr1 * AP + sc];
            #pragma unroll
            for (int j = 0; j < 4; ++j) { d0[j] = f2b(a0v[j]); d1[j] = f2b(a1v[j]); }
        }
        __syncthreads();
    }

    // epilogue: wave-private 32x32 fp32 partial
    // D layout: col = lane&15 (n), row = quad*4 + reg (m)  [verified m89/m91]
    float* pb = part + ((size_t)kc * BSZ + b) * TGT * E;
    #pragma unroll
    for (int r = 0; r < 4; ++r) {
        int rr0 = t0 + quad * 4 + r;
        int rr1 = rr0 + 16;
        int c0  = w * 32 + l15;
        pb[(size_t)rr0 * E + c0]      = acc00[r];
        pb[(size_t)rr0 * E + c0 + 16] = acc01[r];
        pb[(size_t)rr1 * E + c0]      = acc10[r];
        pb[(size_t)rr1 * E + c0 + 16] = acc11[r];
    }
}

// ---------------------------------------------------------------------------
// gemm2_fused: out0[t,b,:] = (sum_kc part[kc])[b,t,:] @ W^T + bias.
// Block = (b, tt16): 128 blocks x 256 thr; blk&7 = b matches gemm1's XCD
// swizzle so the part slices are read back from the same XCD's L2.
// Reduce 8 fp32 partials in registers -> bf16 LDS tile -> A-frags (loaded
// once per wave, reused across 4 et tiles) x W-frags from wf.
// ---------------------------------------------------------------------------
#define PSTRIDE ((size_t)BSZ * TGT * E)

__global__ __launch_bounds__(256) void gemm2_fused(
    const float* __restrict__ part,
    const unsigned short* __restrict__ wf,
    const float* __restrict__ bias,
    float* __restrict__ out0)
{
    __shared__ unsigned short ct[16 * 264];     // 16 t-rows x 256 e, pitch 264
    const int blk  = blockIdx.x;                // 0..127
    const int b    = blk & 7;
    const int tt16 = blk >> 3;                  // 0..15
    const int tid  = threadIdx.x;

    // ---- reduce 8 K-partials into bf16 LDS tile (each element read once)
    const float* pb = part + (size_t)b * TGT * E + (size_t)(tt16 * 16) * E;
    #pragma unroll
    for (int i = 0; i < 4; ++i) {
        int idx = i * 256 + tid;                // 0..1023
        int row = idx >> 6;                     // 0..15
        int c4  = idx & 63;
        const float* ap = pb + (size_t)row * E + c4 * 4;
        f4 s = *(const f4*)ap;
        #pragma unroll
        for (int p = 1; p < 8; ++p) s += *(const f4*)(ap + p * PSTRIDE);
        #pragma unroll
        for (int j = 0; j < 4; ++j) ct[row * 264 + c4 * 4 + j] = f2b(s[j]);
    }
    __syncthreads();

    // ---- MFMA: 4 waves x 4 et tiles each
    const int w    = tid >> 6;
    const int lane = tid & 63;
    const int quad = lane >> 4;
    const int l15  = lane & 15;

    bf16x8 A[8];
    #pragma unroll
    for (int ks = 0; ks < 8; ++ks)
        A[ks] = *(const bf16x8*)&ct[l15 * 264 + ks * 32 + quad * 8];

    #pragma unroll
    for (int e4 = 0; e4 < 4; ++e4) {
        int et = w * 4 + e4;
        const unsigned short* bf = wf + ((size_t)et * 8 * 64 + lane) * 8;
        f32x4 acc = {};
        #pragma unroll
        for (int ks = 0; ks < 8; ++ks) {
            bf16x8 bb = *(const bf16x8*)(bf + (size_t)ks * 512);
            acc = __builtin_amdgcn_mfma_f32_16x16x32_bf16(A[ks], bb, acc, 0, 0, 0);
        }
        const float bval = bias[et * 16 + l15];
        #pragma unroll
        for (int r = 0; r < 4; ++r) {
            int t = tt16 * 16 + quad * 4 + r;
            int e = et * 16 + l15;
            out0[(size_t)t * (BSZ * E) + (size_t)b * E + e] = acc[r] + bval;
        }
    }
}

// ---------------------------------------------------------------------------
extern "C" void kernel_launch(void* const* d_in, const int* in_sizes, int n_in,
                              void* d_out, int out_size, void* d_ws, size_t ws_size,
                              hipStream_t stream)
{
    // inputs: 0=query(unused) 1=key(unused) 2=value 3=proposal_mask 4=W 5=bias
    const float* value = (const float*)d_in[2];
    const float* mask  = (const float*)d_in[3];
    const float* wgt   = (const float*)d_in[4];
    const float* bias  = (const float*)d_in[5];

    float* out0 = (float*)d_out;                              // (256,8,256)
    float* out1 = (float*)d_out + (size_t)TGT * BSZ * E;      // (8,256,4096)

    // ws layout: vtf bf16 16.8MB | wf bf16 128KB | part fp32 [8][b][t][e] 16.8MB
    unsigned short* vtf  = (unsigned short*)d_ws;
    unsigned short* wf   = vtf + (size_t)BSZ * E * SRC;
    float*          part = (float*)(wf + (size_t)16 * 8 * 64 * 8);

    prep<<<dim3(64, 9), 256, 0, stream>>>(value, wgt, vtf, wf);
    gemm1<<<512, 512, 0, stream>>>(mask, vtf, out1, part);
    gemm2_fused<<<128, 256, 0, stream>>>(part, wf, bias, out0);
}